// Round 7
// baseline (260.441 us; speedup 1.0000x reference)
//
#include <hip/hip_runtime.h>
#include <hip/hip_bf16.h>

typedef __attribute__((ext_vector_type(8))) short bf16x8;
typedef __attribute__((ext_vector_type(4))) float f32x4;

#define CAP 64   // fixed per-node edge slot capacity (deg>CAP -> exact fallback)
#define SH  8    // dst shards (== XCD count; blockIdx%8 ~ XCD heuristic)

// fp32 -> bf16 (round-to-nearest-even), bit pattern as ushort
static __device__ inline unsigned short f2b(float f) {
    unsigned u = __float_as_uint(f);
    unsigned r = (u + 0x7FFFu + ((u >> 16) & 1u)) >> 16;
    return (unsigned short)r;
}
// packed bf16 pair -> two fp32
static __device__ inline float blo(unsigned u) { return __uint_as_float(u << 16); }
static __device__ inline float bhi(unsigned u) { return __uint_as_float(u & 0xFFFF0000u); }

// ---------------------------------------------------------------------------
__global__ void zero_kernel(int* __restrict__ p, int n) {
    int i = blockIdx.x * blockDim.x + threadIdx.x;
    if (i < n) p[i] = 0;
}

// ---------------------------------------------------------------------------
// XCD-sharded slot fill. Shard s owns dst in [s*npg, (s+1)*npg); block b
// serves shard b&7 (lands on XCD b&7 -> each node's 128B slot line dirtied by
// one XCD -> single writeback). After this kernel cursor[d] == in-degree(d).
// edge_index int32: row 0 = src (ei[0..E)), row 1 = dst (ei[E..2E)).
// ---------------------------------------------------------------------------
__global__ __launch_bounds__(256) void fill_shard_kernel(
        const int* __restrict__ ei, int* __restrict__ cursor,
        unsigned short* __restrict__ edge16, int E, int N, int G, int npg) {
    int s = blockIdx.x & (SH - 1);
    int i = blockIdx.x >> 3;
    int d_lo = s * npg;
    int d_hi = d_lo + npg; if (d_hi > N) d_hi = N;
    int C = (E + G - 1) / G;
    int e0 = i * C;
    int e1 = e0 + C; if (e1 > E) e1 = E;
    for (int e = e0 + threadIdx.x; e < e1; e += 256) {
        int d = ei[E + e];
        if (d < d_lo || d >= d_hi) continue;
        int src = ei[e];
        if ((unsigned)src >= (unsigned)N) src = 0;   // defensive
        int pos = atomicAdd(&cursor[d], 1);
        if (pos < CAP) edge16[(size_t)d * CAP + pos] = (unsigned short)src;
    }
}

// ---------------------------------------------------------------------------
// fp32 x -> bf16 xb (packed). One float4 -> ushort4 per thread.
// ---------------------------------------------------------------------------
__global__ __launch_bounds__(256) void x2b_kernel(const float* __restrict__ x,
                                                  unsigned short* __restrict__ xb,
                                                  int n4) {
    int i = blockIdx.x * blockDim.x + threadIdx.x;
    if (i >= n4) return;
    float4 v = ((const float4*)x)[i];
    ushort4 b;
    b.x = f2b(v.x); b.y = f2b(v.y); b.z = f2b(v.z); b.w = f2b(v.w);
    ((ushort4*)xb)[i] = b;
}

// ---------------------------------------------------------------------------
// Weight prep (once per call): Wt[layer][n][k] bf16, k-contiguous (transposed)
// k<128 -> Wl[k][n], k>=128 -> Wr[k-128][n]. 64KB per layer.
// ---------------------------------------------------------------------------
__global__ void prep_w_kernel(const float* __restrict__ W1l, const float* __restrict__ W1r,
                              const float* __restrict__ W2l, const float* __restrict__ W2r,
                              unsigned short* __restrict__ wt) {
    int n = blockIdx.x & 127;
    int layer = blockIdx.x >> 7;
    int k = threadIdx.x;           // 0..127
    const float* Wlp = layer ? W2l : W1l;
    const float* Wrp = layer ? W2r : W1r;
    unsigned short* dst = wt + (size_t)layer * 128 * 256 + (size_t)n * 256;
    dst[k]       = f2b(Wlp[(size_t)k * 128 + n]);
    dst[k + 128] = f2b(Wrp[(size_t)k * 128 + n]);
}

// ---------------------------------------------------------------------------
// FUSED layer: aggregate (mean over in-neighbors) + dual GEMM + bias (+ReLU).
// Block = 64 nodes, 256 thr = 4 waves.
// Phase 1a: all threads stage x rows (in[row]) to LDS k=128..255 (uint4).
// Phase 1b: wave w aggregates nodes w*16..w*16+15: lane = g*16+f, group g
//   processes edge j+g, lane covers features f*8..f*8+7 (one 16B gather);
//   cross-group shfl_xor reduce; g==0 lanes write bf16 row to LDS k=0..127.
// Phase 2: MFMA dual-GEMM over K=256 (layouts m89/m120-verified:
//   A[m=lane&15][k=quad*8+j], B[n=lane&15][k=quad*8+j],
//   C/D col=lane&15, row=quad*4+reg).
// Tail (node>=N): LDS rows garbage, but MFMA output row r depends only on A
// row r and stores are row-masked -> safe.
// NOTE: out must NOT alias in (other blocks gather arbitrary rows of in).
// ---------------------------------------------------------------------------
template<int RELU, int OUT_BF16>
__global__ __launch_bounds__(256) void layer_kernel(
        const unsigned short* __restrict__ in, const int* __restrict__ cursor,
        const unsigned short* __restrict__ edge16, const int* __restrict__ ei,
        const unsigned short* __restrict__ Wt, const float* __restrict__ bias,
        void* __restrict__ outp, int E, int N) {
    constexpr int LDK = 264;
    __shared__ unsigned short sA[64 * LDK];
    int tid  = threadIdx.x;
    int lane = tid & 63;
    int wave = tid >> 6;
    int row0 = blockIdx.x * 64;

    // --- stage x rows: 64 rows x 16 uint4 chunks = 1024, 4/thread ---
    #pragma unroll
    for (int it = 0; it < 4; ++it) {
        int c = tid + it * 256;
        int r = c >> 4;              // row 0..63
        int q = c & 15;              // 16B chunk
        int row = row0 + r; if (row >= N) row = N - 1;
        uint4 v = ((const uint4*)(in + (size_t)row * 128))[q];
        *(uint4*)&sA[r * LDK + 128 + q * 8] = v;
    }

    // --- aggregate 16 nodes per wave into LDS k=0..127 ---
    int g = lane >> 4;          // edge group 0..3
    int f = lane & 15;          // feature quarter
    for (int i = 0; i < 16; ++i) {
        int node = row0 + wave * 16 + i;
        if (node >= N) break;
        int deg = cursor[node];
        float acc[8];
        #pragma unroll
        for (int t = 0; t < 8; ++t) acc[t] = 0.f;

        if (deg <= CAP) {
            const unsigned short* base = edge16 + (size_t)node * CAP;
            int idx = (lane < deg) ? (int)base[lane] : 0;   // coalesced preload
            #pragma unroll 4
            for (int j = 0; j < deg; j += 4) {
                int e = j + g;
                int s = __shfl(idx, e & 63);
                if (e < deg) {
                    uint4 v = *(const uint4*)(in + (size_t)s * 128 + f * 8);
                    acc[0] += blo(v.x); acc[1] += bhi(v.x);
                    acc[2] += blo(v.y); acc[3] += bhi(v.y);
                    acc[4] += blo(v.z); acc[5] += bhi(v.z);
                    acc[6] += blo(v.w); acc[7] += bhi(v.w);
                }
            }
        } else {
            // exact fallback: scan the whole edge list (never taken here)
            for (int j = 0; j < E; j += 4) {
                int e = j + g;
                bool act = (e < E) && (ei[E + e] == node);
                if (act) {
                    int s = ei[e];
                    if ((unsigned)s >= (unsigned)N) s = 0;
                    uint4 v = *(const uint4*)(in + (size_t)s * 128 + f * 8);
                    acc[0] += blo(v.x); acc[1] += bhi(v.x);
                    acc[2] += blo(v.y); acc[3] += bhi(v.y);
                    acc[4] += blo(v.z); acc[5] += bhi(v.z);
                    acc[6] += blo(v.w); acc[7] += bhi(v.w);
                }
            }
        }
        // reduce across the 4 edge-groups (xor lanes 16, 32)
        #pragma unroll
        for (int d = 16; d <= 32; d <<= 1) {
            #pragma unroll
            for (int t = 0; t < 8; ++t) acc[t] += __shfl_xor(acc[t], d);
        }
        if (g == 0) {
            float inv = 1.0f / (float)(deg > 1 ? deg : 1);
            uint4 o;
            o.x = (unsigned)f2b(acc[0] * inv) | ((unsigned)f2b(acc[1] * inv) << 16);
            o.y = (unsigned)f2b(acc[2] * inv) | ((unsigned)f2b(acc[3] * inv) << 16);
            o.z = (unsigned)f2b(acc[4] * inv) | ((unsigned)f2b(acc[5] * inv) << 16);
            o.w = (unsigned)f2b(acc[6] * inv) | ((unsigned)f2b(acc[7] * inv) << 16);
            *(uint4*)&sA[(wave * 16 + i) * LDK + f * 8] = o;
        }
    }
    __syncthreads();

    // --- MFMA dual GEMM: wave w covers n in [32w, 32w+32) ---
    int quad = lane >> 4;
    int tm   = lane & 15;

    f32x4 acc[4][2];
    #pragma unroll
    for (int m = 0; m < 4; ++m)
        #pragma unroll
        for (int j = 0; j < 2; ++j)
            acc[m][j] = (f32x4){0.f, 0.f, 0.f, 0.f};

    const unsigned short* wb0 = Wt + (size_t)(wave * 32 + tm) * 256;

    #pragma unroll
    for (int ks = 0; ks < 8; ++ks) {
        int k0 = ks * 32 + quad * 8;
        bf16x8 a[4], b[2];
        #pragma unroll
        for (int m = 0; m < 4; ++m)
            a[m] = *(const bf16x8*)&sA[(m * 16 + tm) * LDK + k0];
        #pragma unroll
        for (int j = 0; j < 2; ++j)
            b[j] = *(const bf16x8*)(wb0 + (size_t)j * 16 * 256 + k0);
        #pragma unroll
        for (int m = 0; m < 4; ++m)
            #pragma unroll
            for (int j = 0; j < 2; ++j)
                acc[m][j] = __builtin_amdgcn_mfma_f32_16x16x32_bf16(a[m], b[j], acc[m][j], 0, 0, 0);
    }

    // epilogue: C/D col=lane&15 (-> ncol), row=quad*4+reg
    #pragma unroll
    for (int j = 0; j < 2; ++j) {
        int ncol = wave * 32 + j * 16 + tm;
        float bb = bias[ncol];
        #pragma unroll
        for (int m = 0; m < 4; ++m) {
            #pragma unroll
            for (int reg = 0; reg < 4; ++reg) {
                int row = row0 + m * 16 + quad * 4 + reg;
                if (row >= N) continue;
                float v = acc[m][j][reg] + bb;
                if (RELU) v = v > 0.f ? v : 0.f;
                if (OUT_BF16)
                    ((unsigned short*)outp)[(size_t)row * 128 + ncol] = f2b(v);
                else
                    ((float*)outp)[(size_t)row * 128 + ncol] = v;
            }
        }
    }
}

// ---------------------------------------------------------------------------
extern "C" void kernel_launch(void* const* d_in, const int* in_sizes, int n_in,
                              void* d_out, int out_size, void* d_ws, size_t ws_size,
                              hipStream_t stream) {
    const float* x   = (const float*)d_in[0];
    const int*   ei  = (const int*)d_in[1];     // int32 (harness converts int64)
    const float* W1l = (const float*)d_in[2];
    const float* b1  = (const float*)d_in[3];
    const float* W1r = (const float*)d_in[4];
    const float* W2l = (const float*)d_in[5];
    const float* b2  = (const float*)d_in[6];
    const float* W2r = (const float*)d_in[7];
    float* out = (float*)d_out;

    const int D = 128;
    const int N = in_sizes[0] / D;     // 50000
    const int E = in_sizes[1] / 2;     // 800000

    // workspace carve-out (512B aligned), ~33 MB total
    char* ws = (char*)d_ws;
    size_t off = 0;
    auto alloc = [&](size_t bytes) {
        size_t o = off;
        off = (off + bytes + 511) & ~(size_t)511;
        return (void*)(ws + o);
    };
    int*            cursor  = (int*)           alloc((size_t)N * 4);
    unsigned short* edge16  = (unsigned short*)alloc((size_t)N * CAP * 2);
    unsigned short* xb      = (unsigned short*)alloc((size_t)N * D * 2);
    unsigned short* h_bf    = (unsigned short*)alloc((size_t)N * D * 2);  // no aliasing (fused gather)
    unsigned short* wt      = (unsigned short*)alloc((size_t)2 * 128 * 256 * 2);
    (void)ws_size; (void)n_in; (void)out_size;

    // 1) slot fill, XCD-sharded (cursor doubles as degree)
    zero_kernel<<<(N + 255) / 256, 256, 0, stream>>>(cursor, N);
    {
        int G = 256;                       // chunks per shard; grid = 8*G
        int npg = (N + SH - 1) / SH;       // nodes per shard
        fill_shard_kernel<<<SH * G, 256, 0, stream>>>(ei, cursor, edge16, E, N, G, npg);
    }

    // 2) bf16 conversions: x -> xb ; weights -> wt[layer][n][k]
    int n4 = N * D / 4;
    x2b_kernel<<<(n4 + 255) / 256, 256, 0, stream>>>(x, xb, n4);
    prep_w_kernel<<<256, 128, 0, stream>>>(W1l, W1r, W2l, W2r, wt);
    const unsigned short* wt1 = wt;
    const unsigned short* wt2 = wt + (size_t)128 * 256;

    int grid = (N + 63) / 64;

    // 3) fused layers (kernel boundary = global barrier between layers)
    layer_kernel<1, 1><<<grid, 256, 0, stream>>>(xb,   cursor, edge16, ei, wt1, b1, (void*)h_bf, E, N);
    layer_kernel<0, 0><<<grid, 256, 0, stream>>>(h_bf, cursor, edge16, ei, wt2, b2, (void*)out,  E, N);
}